// Round 1
// baseline (3094.782 us; speedup 1.0000x reference)
//
#include <hip/hip_runtime.h>
#include <stdint.h>

#define H 64
#define DIN 275
#define DINP 288
#define AHEAD 14

// ---------- small prep kernels ----------
__global__ void k_pad_encw(const float* __restrict__ w, float* __restrict__ wp) {
  int i = blockIdx.x * 256 + threadIdx.x;
  if (i >= 64 * DINP) return;
  int f = i / DINP, k = i % DINP;
  wp[i] = (k < DIN) ? w[f * DIN + k] : 0.f;
}

__global__ void k_init_deg(int* __restrict__ deg, int n) {
  int i = blockIdx.x * 256 + threadIdx.x;
  if (i < n) deg[i] = 1;  // self-loop
}

__global__ void k_deg(const int* __restrict__ dst, int* __restrict__ deg, int e) {
  int i = blockIdx.x * 256 + threadIdx.x;
  if (i < e) atomicAdd(&deg[dst[i]], 1);
}

// ---------- 2-level exclusive scan over deg -> row_start ----------
__global__ void k_scan1(const int* __restrict__ in, int* __restrict__ part,
                        int* __restrict__ bsums, int n) {
  int tid = threadIdx.x;
  int gid = blockIdx.x * 256 + tid;
  int v = (gid < n) ? in[gid] : 0;
  int lane = tid & 63, wv = tid >> 6;
  int x = v;
#pragma unroll
  for (int d = 1; d < 64; d <<= 1) {
    int y = __shfl_up(x, d, 64);
    if (lane >= d) x += y;
  }
  __shared__ int ws_[4];
  if (lane == 63) ws_[wv] = x;
  __syncthreads();
  int off = 0;
  for (int i = 0; i < wv; ++i) off += ws_[i];
  int incl = x + off;
  if (gid < n) part[gid] = incl - v;
  if (tid == 255) bsums[blockIdx.x] = incl;
}

__global__ void k_scan2(int* __restrict__ bsums, int nb) {
  int tid = threadIdx.x;  // block of 1024, nb <= 1024
  int v = (tid < nb) ? bsums[tid] : 0;
  int lane = tid & 63, wv = tid >> 6;
  int x = v;
#pragma unroll
  for (int d = 1; d < 64; d <<= 1) {
    int y = __shfl_up(x, d, 64);
    if (lane >= d) x += y;
  }
  __shared__ int ws_[16];
  if (lane == 63) ws_[wv] = x;
  __syncthreads();
  int off = 0;
  for (int i = 0; i < wv; ++i) off += ws_[i];
  int incl = x + off;
  if (tid < nb) bsums[tid] = incl - v;  // exclusive block offsets
}

__global__ void k_scanfin(const int* __restrict__ part, const int* __restrict__ bsums,
                          const int* __restrict__ deg, int* __restrict__ row_start,
                          int* __restrict__ cursor, float* __restrict__ dis,
                          int n, int total) {
  int gid = blockIdx.x * 256 + threadIdx.x;
  if (gid < n) {
    int rs = part[gid] + bsums[gid >> 8];
    row_start[gid] = rs;
    cursor[gid] = rs;
    dis[gid] = rsqrtf((float)deg[gid]);  // deg >= 1 always (self-loop)
  } else if (gid == n) {
    row_start[n] = total;
  }
}

__global__ void k_fill(const int* __restrict__ src, const int* __restrict__ dst,
                       int* __restrict__ cursor, int* __restrict__ csr, int e, int n) {
  int i = blockIdx.x * 256 + threadIdx.x;
  if (i >= e + n) return;
  int s, d;
  if (i < e) { s = src[i]; d = dst[i]; }
  else       { s = i - e; d = s; }      // self loops
  int pos = atomicAdd(&cursor[d], 1);
  csr[pos] = s;
}

// ---------- encoder: lane = node, wave-uniform weights via s_load ----------
// v2: 32-col swizzled LDS tile (32KB/block -> 5 blocks/CU), b128 LDS reads,
// direct per-lane output stores. __launch_bounds__(256,4) caps VGPR at 128
// (need ~100: h1[64] + xr[32] + temps) -> 16 waves/CU.
__global__ __launch_bounds__(256, 4) void k_enc(
    const float* __restrict__ inp, const float* __restrict__ wenc,
    const float* __restrict__ benc, float* __restrict__ h1o, int n) {
  __shared__ float X[4][64 * 32];  // per-wave tile, XOR-swizzled on 4-dword groups
  int tid = threadIdx.x;
  int wv = tid >> 6, lane = tid & 63;
  long long group = (long long)blockIdx.x * 4 + wv;
  long long node0 = group * 64;
  bool dead = node0 >= n;
  if (dead) node0 = 0;
  float* Xw = X[wv];

  float h1[64];
#pragma unroll
  for (int f = 0; f < 64; ++f) h1[f] = benc[f];

  for (int kc = 0; kc < DINP; kc += 32) {
    // stage 64 rows x 32 cols (2 rows per load instruction, 128B segments)
#pragma unroll
    for (int r2 = 0; r2 < 32; ++r2) {
      int row = r2 * 2 + (lane >> 5);
      int col = lane & 31;
      int k = kc + col;
      long long nd = node0 + row;
      float v = 0.f;
      if (k < DIN && nd < n) v = inp[nd * DIN + k];
      // swizzle: spread each column across banks, keep 16B groups contiguous
      Xw[row * 32 + (((col >> 2) ^ (row & 7)) << 2) + (col & 3)] = v;
    }
    // wave-private tile: intra-wave LDS ordering suffices, no __syncthreads
    float xr[32];
#pragma unroll
    for (int kg = 0; kg < 8; ++kg) {
      float4 t = *(const float4*)&Xw[lane * 32 + ((kg ^ (lane & 7)) << 2)];
      xr[kg * 4 + 0] = t.x; xr[kg * 4 + 1] = t.y;
      xr[kg * 4 + 2] = t.z; xr[kg * 4 + 3] = t.w;
    }
    const float* wp = wenc + kc;
#pragma unroll
    for (int f = 0; f < 64; ++f) {
#pragma unroll
      for (int kk = 0; kk < 32; ++kk)
        h1[f] = fmaf(wp[f * DINP + kk], xr[kk], h1[f]);  // weight via s_load (uniform)
    }
  }

  // relu + direct per-lane row store (row = 256B aligned; L2 merges 16B chunks)
  long long nodeL = node0 + lane;
  if (nodeL < n && !dead) {
    float* ob = h1o + nodeL * 64;
#pragma unroll
    for (int q = 0; q < 16; ++q) {
      float4 t;
      t.x = fmaxf(h1[4 * q + 0], 0.f);
      t.y = fmaxf(h1[4 * q + 1], 0.f);
      t.z = fmaxf(h1[4 * q + 2], 0.f);
      t.w = fmaxf(h1[4 * q + 3], 0.f);
      *(float4*)(ob + 4 * q) = t;
    }
  }
}

// ---------- GRU v2: thread = node, NO LDS, x and h both in registers ----------
// f-loop blocked by 4 (24 static accumulators), output streamed as float4 per
// f-quad => no h2r[64] array, no spill. ~170 VGPR under the (256,2) 256-reg cap.
// The one runtime-indexed read (h[f] for the z*h term) is done via a
// wave-uniform 16-way scalar-branch select (all reg indices compile-time).
__global__ __launch_bounds__(256, 2) void k_gru(
    const float* __restrict__ h1g, const float* __restrict__ hid,
    const float* __restrict__ wih, const float* __restrict__ whh,
    const float* __restrict__ bih, const float* __restrict__ bhh,
    float* __restrict__ h2o, int n) {
  long long node = (long long)blockIdx.x * 256 + threadIdx.x;
  bool act = node < n;
  long long nc = act ? node : 0;

  float xr[64], hr[64];
  const float4* xp = (const float4*)(h1g + nc * 64);
  const float4* hp = (const float4*)(hid + nc * 64);
#pragma unroll
  for (int q = 0; q < 16; ++q) {
    float4 t = xp[q];
    xr[4 * q + 0] = t.x; xr[4 * q + 1] = t.y;
    xr[4 * q + 2] = t.z; xr[4 * q + 3] = t.w;
    float4 u = hp[q];
    hr[4 * q + 0] = u.x; hr[4 * q + 1] = u.y;
    hr[4 * q + 2] = u.z; hr[4 * q + 3] = u.w;
  }

  float* orow = h2o + nc * 64;
  for (int fq = 0; fq < 16; ++fq) {
    float accI[3][4], accH[3][4];
#pragma unroll
    for (int g = 0; g < 3; ++g)
#pragma unroll
      for (int fi = 0; fi < 4; ++fi) {
        accI[g][fi] = bih[g * 64 + fq * 4 + fi];
        accH[g][fi] = bhh[g * 64 + fq * 4 + fi];
      }
#pragma unroll
    for (int k = 0; k < 64; ++k) {
      float a = xr[k];
      float b = hr[k];
#pragma unroll
      for (int g = 0; g < 3; ++g)
#pragma unroll
        for (int fi = 0; fi < 4; ++fi) {
          accI[g][fi] = fmaf(wih[(g * 64 + fq * 4 + fi) * 64 + k], a, accI[g][fi]);
          accH[g][fi] = fmaf(whh[(g * 64 + fq * 4 + fi) * 64 + k], b, accH[g][fi]);
        }
    }
    // wave-uniform select of h[4*fq .. 4*fq+3] (fq is uniform -> scalar branch,
    // all hr indices compile-time => stays in registers)
    float hf0 = 0.f, hf1 = 0.f, hf2 = 0.f, hf3 = 0.f;
#pragma unroll
    for (int q = 0; q < 16; ++q) {
      if (q == fq) {
        hf0 = hr[4 * q + 0]; hf1 = hr[4 * q + 1];
        hf2 = hr[4 * q + 2]; hf3 = hr[4 * q + 3];
      }
    }
    float hfv[4] = {hf0, hf1, hf2, hf3};
    float ov[4];
#pragma unroll
    for (int fi = 0; fi < 4; ++fi) {
      float r = 1.f / (1.f + __expf(-(accI[0][fi] + accH[0][fi])));
      float z = 1.f / (1.f + __expf(-(accI[1][fi] + accH[1][fi])));
      float nn = tanhf(accI[2][fi] + r * accH[2][fi]);
      ov[fi] = (1.f - z) * nn + z * hfv[fi];
    }
    if (act) {
      float4 t;
      t.x = ov[0]; t.y = ov[1]; t.z = ov[2]; t.w = ov[3];
      *(float4*)(orow + fq * 4) = t;
    }
  }
}

// ---------- y = x @ W^T, W [64][64] row-major; thread = node ----------
__global__ void k_gemv64(const float* __restrict__ x, const float* __restrict__ W,
                         float* __restrict__ y, int n) {
  int node = blockIdx.x * 256 + threadIdx.x;
  if (node >= n) return;
  float xr[64];
  const float4* xp = (const float4*)(x + (size_t)node * 64);
#pragma unroll
  for (int q = 0; q < 16; ++q) {
    float4 t = xp[q];
    xr[q * 4 + 0] = t.x; xr[q * 4 + 1] = t.y;
    xr[q * 4 + 2] = t.z; xr[q * 4 + 3] = t.w;
  }
  float* yo = y + (size_t)node * 64;
#pragma unroll 4
  for (int f = 0; f < 64; ++f) {
    float acc = 0.f;
    const float* wr = W + f * 64;
#pragma unroll
    for (int k = 0; k < 64; ++k) acc = fmaf(wr[k], xr[k], acc);
    yo[f] = acc;
  }
}

// ---------- gather aggregation: wave = dst node, lane = feature ----------
// v2: 8-deep independent loads in flight; (256,8) caps VGPR at 64 (need ~40).
__global__ __launch_bounds__(256, 8) void k_agg(
    const float* __restrict__ y, const int* __restrict__ row_start,
    const int* __restrict__ csr, const float* __restrict__ dis,
    const float* __restrict__ bias, float* __restrict__ out,
    int n, int dorelu) {
  int t = blockIdx.x * 256 + threadIdx.x;
  int w = t >> 6;
  int lane = t & 63;
  if (w >= n) return;
  w = __builtin_amdgcn_readfirstlane(w);  // wave-uniform -> scalar path
  int beg = row_start[w], end = row_start[w + 1];
  float acc = 0.f;
  int i = beg;
  for (; i + 8 <= end; i += 8) {
    int s0 = csr[i + 0], s1 = csr[i + 1], s2 = csr[i + 2], s3 = csr[i + 3];
    int s4 = csr[i + 4], s5 = csr[i + 5], s6 = csr[i + 6], s7 = csr[i + 7];
    float n0 = dis[s0], n1 = dis[s1], n2 = dis[s2], n3 = dis[s3];
    float n4 = dis[s4], n5 = dis[s5], n6 = dis[s6], n7 = dis[s7];
    float v0 = y[(size_t)s0 * 64 + lane];
    float v1 = y[(size_t)s1 * 64 + lane];
    float v2 = y[(size_t)s2 * 64 + lane];
    float v3 = y[(size_t)s3 * 64 + lane];
    float v4 = y[(size_t)s4 * 64 + lane];
    float v5 = y[(size_t)s5 * 64 + lane];
    float v6 = y[(size_t)s6 * 64 + lane];
    float v7 = y[(size_t)s7 * 64 + lane];
    acc += v0 * n0 + v1 * n1 + v2 * n2 + v3 * n3;
    acc += v4 * n4 + v5 * n5 + v6 * n6 + v7 * n7;
  }
  for (; i + 4 <= end; i += 4) {
    int s0 = csr[i], s1 = csr[i + 1], s2 = csr[i + 2], s3 = csr[i + 3];
    float n0 = dis[s0], n1 = dis[s1], n2 = dis[s2], n3 = dis[s3];
    float v0 = y[(size_t)s0 * 64 + lane];
    float v1 = y[(size_t)s1 * 64 + lane];
    float v2 = y[(size_t)s2 * 64 + lane];
    float v3 = y[(size_t)s3 * 64 + lane];
    acc += v0 * n0 + v1 * n1 + v2 * n2 + v3 * n3;
  }
  for (; i < end; ++i) {
    int s = csr[i];
    acc += y[(size_t)s * 64 + lane] * dis[s];
  }
  acc = acc * dis[w] + bias[lane];
  if (dorelu) acc = fmaxf(acc, 0.f);
  out[(size_t)w * 64 + lane] = acc;
}

// ---------- Q head ----------
__global__ void k_qhead(const float* __restrict__ h3, const float* __restrict__ qw,
                        const float* __restrict__ qb, float* __restrict__ qout, int n) {
  int node = blockIdx.x * 256 + threadIdx.x;
  if (node >= n) return;
  float xr[64];
  const float4* xp = (const float4*)(h3 + (size_t)node * 64);
#pragma unroll
  for (int q = 0; q < 16; ++q) {
    float4 t = xp[q];
    xr[q * 4 + 0] = t.x; xr[q * 4 + 1] = t.y;
    xr[q * 4 + 2] = t.z; xr[q * 4 + 3] = t.w;
  }
  float* qo = qout + (size_t)node * AHEAD;
#pragma unroll 2
  for (int a = 0; a < AHEAD; ++a) {
    float acc = qb[a];
    const float* wr = qw + a * 64;
#pragma unroll
    for (int k = 0; k < 64; ++k) acc = fmaf(wr[k], xr[k], acc);
    qo[a] = acc;
  }
}

extern "C" void kernel_launch(void* const* d_in, const int* in_sizes, int n_in,
                              void* d_out, int out_size, void* d_ws, size_t ws_size,
                              hipStream_t stream) {
  const float* inp  = (const float*)d_in[0];
  const float* hid  = (const float*)d_in[1];
  const int*   eidx = (const int*)d_in[2];
  const float* encw = (const float*)d_in[3];
  const float* encb = (const float*)d_in[4];
  const float* wih  = (const float*)d_in[5];
  const float* whh  = (const float*)d_in[6];
  const float* bih  = (const float*)d_in[7];
  const float* bhh  = (const float*)d_in[8];
  const float* g1w  = (const float*)d_in[9];
  const float* g1b  = (const float*)d_in[10];
  const float* g2w  = (const float*)d_in[11];
  const float* g2b  = (const float*)d_in[12];
  const float* qw   = (const float*)d_in[13];
  const float* qb   = (const float*)d_in[14];

  int n = in_sizes[1] / H;   // 200000
  int e = in_sizes[2] / 2;   // 3200000
  const int* esrc = eidx;
  const int* edst = eidx + e;

  float* qout = (float*)d_out;
  float* h2o  = (float*)d_out + (size_t)n * AHEAD;

  // workspace carve (~175 MB)
  char* w = (char*)d_ws;
  float* wencp   = (float*)w; w += (size_t)64 * DINP * 4;
  int* deg       = (int*)w;   w += (size_t)n * 4;
  int* part      = (int*)w;   w += (size_t)n * 4;
  int* bsums     = (int*)w;   w += 4096;
  int* row_start = (int*)w;   w += ((size_t)n + 1) * 4;
  int* cursor    = (int*)w;   w += (size_t)n * 4;
  float* dis     = (float*)w; w += (size_t)n * 4;
  int* csr       = (int*)w;   w += (size_t)(e + n) * 4;
  w = (char*)(((uintptr_t)w + 15) & ~(uintptr_t)15);
  float* h1buf   = (float*)w; w += (size_t)n * H * 4;
  float* ybuf    = (float*)w; w += (size_t)n * H * 4;
  float* xbuf    = (float*)w; w += (size_t)n * H * 4;

  int nb = (n + 255) / 256;
  int total = e + n;

  hipLaunchKernelGGL(k_pad_encw, dim3((64 * DINP + 255) / 256), dim3(256), 0, stream, encw, wencp);
  hipLaunchKernelGGL(k_init_deg, dim3(nb), dim3(256), 0, stream, deg, n);
  hipLaunchKernelGGL(k_deg, dim3((e + 255) / 256), dim3(256), 0, stream, edst, deg, e);
  hipLaunchKernelGGL(k_scan1, dim3(nb), dim3(256), 0, stream, deg, part, bsums, n);
  hipLaunchKernelGGL(k_scan2, dim3(1), dim3(1024), 0, stream, bsums, nb);
  hipLaunchKernelGGL(k_scanfin, dim3((n + 1 + 255) / 256), dim3(256), 0, stream,
                     part, bsums, deg, row_start, cursor, dis, n, total);
  hipLaunchKernelGGL(k_fill, dim3((total + 255) / 256), dim3(256), 0, stream,
                     esrc, edst, cursor, csr, e, n);

  int groups = (n + 63) / 64;
  int gblocks = (groups + 3) / 4;
  hipLaunchKernelGGL(k_enc, dim3(gblocks), dim3(256), 0, stream,
                     inp, wencp, encb, h1buf, n);
  hipLaunchKernelGGL(k_gru, dim3(nb), dim3(256), 0, stream,
                     h1buf, hid, wih, whh, bih, bhh, h2o, n);

  int aggblocks = (int)(((size_t)n * 64 + 255) / 256);
  hipLaunchKernelGGL(k_gemv64, dim3(nb), dim3(256), 0, stream, h2o, g1w, ybuf, n);
  hipLaunchKernelGGL(k_agg, dim3(aggblocks), dim3(256), 0, stream,
                     ybuf, row_start, csr, dis, g1b, xbuf, n, 1);
  hipLaunchKernelGGL(k_gemv64, dim3(nb), dim3(256), 0, stream, xbuf, g2w, ybuf, n);
  hipLaunchKernelGGL(k_agg, dim3(aggblocks), dim3(256), 0, stream,
                     ybuf, row_start, csr, dis, g2b, xbuf, n, 0);
  hipLaunchKernelGGL(k_qhead, dim3(nb), dim3(256), 0, stream, xbuf, qw, qb, qout, n);
}

// Round 2
// 1382.065 us; speedup vs baseline: 2.2392x; 2.2392x over previous
//
#include <hip/hip_runtime.h>
#include <stdint.h>

#define H 64
#define DIN 275
#define AHEAD 14

typedef __attribute__((ext_vector_type(8))) short s16x8;   // 8 bf16 = 4 VGPR
typedef __attribute__((ext_vector_type(4))) float f32x4;

#define MFMA16(a, b, c) __builtin_amdgcn_mfma_f32_16x16x32_bf16((a), (b), (c), 0, 0, 0)

__device__ __forceinline__ unsigned short bf16_rn(float x) {
  unsigned u = __float_as_uint(x);
  return (unsigned short)((u + 0x7FFFu + ((u >> 16) & 1u)) >> 16);
}
__device__ __forceinline__ float bf16f(unsigned short h) {
  return __uint_as_float(((unsigned)h) << 16);
}
// split 8 fp32 -> bf16 hi + bf16 lo fragments (error ~2^-17 rel)
__device__ __forceinline__ void cvt8(const float (&v)[8], s16x8& hi, s16x8& lo) {
#pragma unroll
  for (int j = 0; j < 8; ++j) {
    unsigned short h = bf16_rn(v[j]);
    hi[j] = (short)h;
    lo[j] = (short)bf16_rn(v[j] - bf16f(h));
  }
}

// ---------- weight pre-pack into B-fragment layout (gemm_bt convention) ----------
// W row-major [F_real x K_real], used as Y = X @ W^T.
// frag tile (kt, ft): lane holds W[ft*16 + (lane&15)][kt*32 + (lane>>4)*8 + j], j=0..7
// pack layout (ushort): [((kt*FT + ft)*2 + hilo)*512 + lane*8 + j]
__global__ void k_packw(const float* __restrict__ W, int F_real, int K_real,
                        int KT, int FT, unsigned short* __restrict__ pack) {
  int idx = blockIdx.x * 256 + threadIdx.x;
  int total = KT * FT * 64;
  if (idx >= total) return;
  int lane = idx & 63;
  int t = idx >> 6;
  int ft = t % FT, kt = t / FT;
  int f = ft * 16 + (lane & 15);
  int kb = kt * 32 + (lane >> 4) * 8;
  unsigned short* base = pack + (size_t)(kt * FT + ft) * 2 * 512;
#pragma unroll
  for (int j = 0; j < 8; ++j) {
    int k = kb + j;
    float v = (f < F_real && k < K_real) ? W[(size_t)f * K_real + k] : 0.f;
    unsigned short h = bf16_rn(v);
    base[lane * 8 + j] = h;
    base[512 + lane * 8 + j] = bf16_rn(v - bf16f(h));
  }
}

// ---------- graph prep ----------
__global__ void k_init_deg(int* __restrict__ deg, int n) {
  int i = blockIdx.x * 256 + threadIdx.x;
  if (i < n) deg[i] = 1;  // self-loop
}

__global__ void k_deg(const int* __restrict__ dst, int* __restrict__ deg, int e) {
  int i = blockIdx.x * 256 + threadIdx.x;
  if (i < e) atomicAdd(&deg[dst[i]], 1);
}

__global__ void k_scan1(const int* __restrict__ in, int* __restrict__ part,
                        int* __restrict__ bsums, int n) {
  int tid = threadIdx.x;
  int gid = blockIdx.x * 256 + tid;
  int v = (gid < n) ? in[gid] : 0;
  int lane = tid & 63, wv = tid >> 6;
  int x = v;
#pragma unroll
  for (int d = 1; d < 64; d <<= 1) {
    int y = __shfl_up(x, d, 64);
    if (lane >= d) x += y;
  }
  __shared__ int ws_[4];
  if (lane == 63) ws_[wv] = x;
  __syncthreads();
  int off = 0;
  for (int i = 0; i < wv; ++i) off += ws_[i];
  int incl = x + off;
  if (gid < n) part[gid] = incl - v;
  if (tid == 255) bsums[blockIdx.x] = incl;
}

__global__ void k_scan2(int* __restrict__ bsums, int nb) {
  int tid = threadIdx.x;  // block of 1024, nb <= 1024
  int v = (tid < nb) ? bsums[tid] : 0;
  int lane = tid & 63, wv = tid >> 6;
  int x = v;
#pragma unroll
  for (int d = 1; d < 64; d <<= 1) {
    int y = __shfl_up(x, d, 64);
    if (lane >= d) x += y;
  }
  __shared__ int ws_[16];
  if (lane == 63) ws_[wv] = x;
  __syncthreads();
  int off = 0;
  for (int i = 0; i < wv; ++i) off += ws_[i];
  int incl = x + off;
  if (tid < nb) bsums[tid] = incl - v;
}

__global__ void k_scanfin(const int* __restrict__ part, const int* __restrict__ bsums,
                          const int* __restrict__ deg, int* __restrict__ row_start,
                          int* __restrict__ cursor, float* __restrict__ dis,
                          int n, int total) {
  int gid = blockIdx.x * 256 + threadIdx.x;
  if (gid < n) {
    int rs = part[gid] + bsums[gid >> 8];
    row_start[gid] = rs;
    cursor[gid] = rs;
    dis[gid] = rsqrtf((float)deg[gid]);
  } else if (gid == n) {
    row_start[n] = total;
  }
}

__global__ void k_fill(const int* __restrict__ src, const int* __restrict__ dst,
                       int* __restrict__ cursor, int* __restrict__ csr, int e, int n) {
  int i = blockIdx.x * 256 + threadIdx.x;
  if (i >= e + n) return;
  int s, d;
  if (i < e) { s = src[i]; d = dst[i]; }
  else       { s = i - e; d = s; }
  int pos = atomicAdd(&cursor[d], 1);
  csr[pos] = s;
}

// ---------- encoder via MFMA: wave = 16 nodes, K = 275 (9 chunks of 32) ----------
// Stage 16 contiguous fp32 rows (17600B) in per-wave LDS, build A-frags with
// in-register bf16 hi/lo split, B from pre-packed fragments (L2-resident).
__global__ __launch_bounds__(128, 2) void k_enc_mfma(
    const float* __restrict__ inp, const unsigned short* __restrict__ wp,
    const float* __restrict__ benc, float* __restrict__ h1o, int n) {
  __shared__ float lds[2][16 * DIN];  // 2 waves x 17600B = 35200B/block
  int tid = threadIdx.x;
  int wv = tid >> 6, lane = tid & 63;
  long long node0 = ((long long)blockIdx.x * 2 + wv) * 16;
  if (node0 >= n) return;
  float* L = lds[wv];

  // flat coalesced copy: rows are contiguous (row stride == DIN)
  const float4* src = (const float4*)(inp + (size_t)node0 * DIN);
#pragma unroll
  for (int i = 0; i < 17; ++i) {
    float4 t = src[i * 64 + lane];
    *(float4*)(L + (i * 64 + lane) * 4) = t;
  }
  if (lane < 48) L[4352 + lane] = inp[(size_t)node0 * DIN + 4352 + lane];
  // wave-private LDS: compiler-inserted lgkmcnt ordering suffices, no barrier

  int r = lane & 15, kq = lane >> 4;
  f32x4 acc[4];
#pragma unroll
  for (int i = 0; i < 4; ++i) acc[i] = (f32x4){0.f, 0.f, 0.f, 0.f};

  const s16x8* bp = (const s16x8*)wp;
#pragma unroll
  for (int kc = 0; kc < 9; ++kc) {
    int kb = kc * 32 + kq * 8;
    float vv[8];
#pragma unroll
    for (int j = 0; j < 8; ++j) {
      int k = kb + j;
      float t = 0.f;
      if (kc < 8 || k < DIN) t = L[r * DIN + k];  // kc<8 folds at compile time
      vv[j] = t;
    }
    s16x8 ah, al;
    cvt8(vv, ah, al);
#pragma unroll
    for (int ft = 0; ft < 4; ++ft) {
      s16x8 bh = bp[((kc * 4 + ft) * 2 + 0) * 64 + lane];
      s16x8 bl = bp[((kc * 4 + ft) * 2 + 1) * 64 + lane];
      acc[ft] = MFMA16(ah, bh, acc[ft]);
      acc[ft] = MFMA16(al, bh, acc[ft]);
      acc[ft] = MFMA16(ah, bl, acc[ft]);
    }
  }

  // epilogue: bias + relu; C layout: col = lane&15 (feature), row = (lane>>4)*4+reg
  int fc = lane & 15, rq = lane >> 4;
#pragma unroll
  for (int ft = 0; ft < 4; ++ft) {
    float b = benc[ft * 16 + fc];
#pragma unroll
    for (int rg = 0; rg < 4; ++rg) {
      long long node = node0 + rq * 4 + rg;
      if (node < n)
        h1o[(size_t)node * 64 + ft * 16 + fc] = fmaxf(acc[ft][rg] + b, 0.f);
    }
  }
}

// ---------- GRU via MFMA: wave = 16 nodes; gi = x@Wih^T, gh = h@Whh^T (F=192) ----------
__global__ __launch_bounds__(256, 2) void k_gru_mfma(
    const float* __restrict__ h1g, const float* __restrict__ hid,
    const unsigned short* __restrict__ wpih, const unsigned short* __restrict__ wphh,
    const float* __restrict__ bih, const float* __restrict__ bhh,
    float* __restrict__ h2o, int n) {
  int tid = threadIdx.x;
  int wv = tid >> 6, lane = tid & 63;
  long long node0 = ((long long)blockIdx.x * 4 + wv) * 16;
  if (node0 >= n) return;
  int r = lane & 15, kq = lane >> 4;

  // A-fragments for x (h1) and h (hid): 2 k-chunks, hi+lo each
  s16x8 xh[2], xl[2], hh[2], hl[2];
#pragma unroll
  for (int kc = 0; kc < 2; ++kc) {
    float vv[8];
    const float4* p = (const float4*)(h1g + (size_t)(node0 + r) * 64 + kc * 32 + kq * 8);
    float4 a = p[0], b = p[1];
    vv[0] = a.x; vv[1] = a.y; vv[2] = a.z; vv[3] = a.w;
    vv[4] = b.x; vv[5] = b.y; vv[6] = b.z; vv[7] = b.w;
    cvt8(vv, xh[kc], xl[kc]);
    const float4* q = (const float4*)(hid + (size_t)(node0 + r) * 64 + kc * 32 + kq * 8);
    float4 c = q[0], d = q[1];
    vv[0] = c.x; vv[1] = c.y; vv[2] = c.z; vv[3] = c.w;
    vv[4] = d.x; vv[5] = d.y; vv[6] = d.z; vv[7] = d.w;
    cvt8(vv, hh[kc], hl[kc]);
  }

  f32x4 ai[12], ag[12];  // gi (x-gemm), gh (h-gemm) accumulators, 12 ftiles each
#pragma unroll
  for (int i = 0; i < 12; ++i) {
    ai[i] = (f32x4){0.f, 0.f, 0.f, 0.f};
    ag[i] = (f32x4){0.f, 0.f, 0.f, 0.f};
  }

  const s16x8* bpI = (const s16x8*)wpih;
  const s16x8* bpH = (const s16x8*)wphh;
#pragma unroll
  for (int kc = 0; kc < 2; ++kc) {
#pragma unroll
    for (int ft = 0; ft < 12; ++ft) {
      int t = (kc * 12 + ft) * 2;
      s16x8 bh = bpI[(t + 0) * 64 + lane];
      s16x8 bl = bpI[(t + 1) * 64 + lane];
      ai[ft] = MFMA16(xh[kc], bh, ai[ft]);
      ai[ft] = MFMA16(xl[kc], bh, ai[ft]);
      ai[ft] = MFMA16(xh[kc], bl, ai[ft]);
      s16x8 ch = bpH[(t + 0) * 64 + lane];
      s16x8 cl = bpH[(t + 1) * 64 + lane];
      ag[ft] = MFMA16(hh[kc], ch, ag[ft]);
      ag[ft] = MFMA16(hl[kc], ch, ag[ft]);
      ag[ft] = MFMA16(hh[kc], cl, ag[ft]);
    }
  }

  // epilogue: gate math per (ftile, reg); ftiles 0-3 = r, 4-7 = z, 8-11 = n
  int fc = lane & 15, rq = lane >> 4;
#pragma unroll
  for (int ft = 0; ft < 4; ++ft) {
    int f = ft * 16 + fc;
    float bir = bih[f], biz = bih[64 + f], bin = bih[128 + f];
    float bhr = bhh[f], bhz = bhh[64 + f], bhn = bhh[128 + f];
#pragma unroll
    for (int rg = 0; rg < 4; ++rg) {
      long long node = node0 + rq * 4 + rg;
      float ir = ai[ft][rg] + bir, hr2 = ag[ft][rg] + bhr;
      float iz = ai[ft + 4][rg] + biz, hz = ag[ft + 4][rg] + bhz;
      float in2 = ai[ft + 8][rg] + bin, hn = ag[ft + 8][rg] + bhn;
      float rr = 1.f / (1.f + __expf(-(ir + hr2)));
      float zz = 1.f / (1.f + __expf(-(iz + hz)));
      float nn = tanhf(in2 + rr * hn);
      float hprev = hid[(size_t)node * 64 + f];
      if (node < n)
        h2o[(size_t)node * 64 + f] = (1.f - zz) * nn + zz * hprev;
    }
  }
}

// ---------- GCN linear via MFMA: y = x @ W^T, W [64x64] ----------
__global__ __launch_bounds__(256, 4) void k_lin_mfma(
    const float* __restrict__ x, const unsigned short* __restrict__ wp,
    float* __restrict__ y, int n) {
  int tid = threadIdx.x;
  int wv = tid >> 6, lane = tid & 63;
  long long node0 = ((long long)blockIdx.x * 4 + wv) * 16;
  if (node0 >= n) return;
  int r = lane & 15, kq = lane >> 4;

  s16x8 ah[2], al[2];
#pragma unroll
  for (int kc = 0; kc < 2; ++kc) {
    float vv[8];
    const float4* p = (const float4*)(x + (size_t)(node0 + r) * 64 + kc * 32 + kq * 8);
    float4 a = p[0], b = p[1];
    vv[0] = a.x; vv[1] = a.y; vv[2] = a.z; vv[3] = a.w;
    vv[4] = b.x; vv[5] = b.y; vv[6] = b.z; vv[7] = b.w;
    cvt8(vv, ah[kc], al[kc]);
  }

  f32x4 acc[4];
#pragma unroll
  for (int i = 0; i < 4; ++i) acc[i] = (f32x4){0.f, 0.f, 0.f, 0.f};
  const s16x8* bp = (const s16x8*)wp;
#pragma unroll
  for (int kc = 0; kc < 2; ++kc) {
#pragma unroll
    for (int ft = 0; ft < 4; ++ft) {
      int t = (kc * 4 + ft) * 2;
      s16x8 bh = bp[(t + 0) * 64 + lane];
      s16x8 bl = bp[(t + 1) * 64 + lane];
      acc[ft] = MFMA16(ah[kc], bh, acc[ft]);
      acc[ft] = MFMA16(al[kc], bh, acc[ft]);
      acc[ft] = MFMA16(ah[kc], bl, acc[ft]);
    }
  }

  int fc = lane & 15, rq = lane >> 4;
#pragma unroll
  for (int ft = 0; ft < 4; ++ft)
#pragma unroll
    for (int rg = 0; rg < 4; ++rg) {
      long long node = node0 + rq * 4 + rg;
      if (node < n) y[(size_t)node * 64 + ft * 16 + fc] = acc[ft][rg];
    }
}

// ---------- Q head via MFMA: F = 16 (14 real) ----------
__global__ __launch_bounds__(256, 4) void k_q_mfma(
    const float* __restrict__ x, const unsigned short* __restrict__ wp,
    const float* __restrict__ qb, float* __restrict__ qout, int n) {
  int tid = threadIdx.x;
  int wv = tid >> 6, lane = tid & 63;
  long long node0 = ((long long)blockIdx.x * 4 + wv) * 16;
  if (node0 >= n) return;
  int r = lane & 15, kq = lane >> 4;

  s16x8 ah[2], al[2];
#pragma unroll
  for (int kc = 0; kc < 2; ++kc) {
    float vv[8];
    const float4* p = (const float4*)(x + (size_t)(node0 + r) * 64 + kc * 32 + kq * 8);
    float4 a = p[0], b = p[1];
    vv[0] = a.x; vv[1] = a.y; vv[2] = a.z; vv[3] = a.w;
    vv[4] = b.x; vv[5] = b.y; vv[6] = b.z; vv[7] = b.w;
    cvt8(vv, ah[kc], al[kc]);
  }

  f32x4 acc = (f32x4){0.f, 0.f, 0.f, 0.f};
  const s16x8* bp = (const s16x8*)wp;
#pragma unroll
  for (int kc = 0; kc < 2; ++kc) {
    s16x8 bh = bp[(kc * 2 + 0) * 64 + lane];
    s16x8 bl = bp[(kc * 2 + 1) * 64 + lane];
    acc = MFMA16(ah[kc], bh, acc);
    acc = MFMA16(al[kc], bh, acc);
    acc = MFMA16(ah[kc], bl, acc);
  }

  int fc = lane & 15, rq = lane >> 4;
  float b = (fc < AHEAD) ? qb[fc] : 0.f;
#pragma unroll
  for (int rg = 0; rg < 4; ++rg) {
    long long node = node0 + rq * 4 + rg;
    if (fc < AHEAD && node < n) qout[(size_t)node * AHEAD + fc] = acc[rg] + b;
  }
}

// ---------- gather aggregation: wave = dst node, lane = feature ----------
__global__ __launch_bounds__(256, 8) void k_agg(
    const float* __restrict__ y, const int* __restrict__ row_start,
    const int* __restrict__ csr, const float* __restrict__ dis,
    const float* __restrict__ bias, float* __restrict__ out,
    int n, int dorelu) {
  int t = blockIdx.x * 256 + threadIdx.x;
  int w = t >> 6;
  int lane = t & 63;
  if (w >= n) return;
  w = __builtin_amdgcn_readfirstlane(w);
  int beg = row_start[w], end = row_start[w + 1];
  float acc = 0.f;
  int i = beg;
  for (; i + 8 <= end; i += 8) {
    int s0 = csr[i + 0], s1 = csr[i + 1], s2 = csr[i + 2], s3 = csr[i + 3];
    int s4 = csr[i + 4], s5 = csr[i + 5], s6 = csr[i + 6], s7 = csr[i + 7];
    float n0 = dis[s0], n1 = dis[s1], n2 = dis[s2], n3 = dis[s3];
    float n4 = dis[s4], n5 = dis[s5], n6 = dis[s6], n7 = dis[s7];
    float v0 = y[(size_t)s0 * 64 + lane];
    float v1 = y[(size_t)s1 * 64 + lane];
    float v2 = y[(size_t)s2 * 64 + lane];
    float v3 = y[(size_t)s3 * 64 + lane];
    float v4 = y[(size_t)s4 * 64 + lane];
    float v5 = y[(size_t)s5 * 64 + lane];
    float v6 = y[(size_t)s6 * 64 + lane];
    float v7 = y[(size_t)s7 * 64 + lane];
    acc += v0 * n0 + v1 * n1 + v2 * n2 + v3 * n3;
    acc += v4 * n4 + v5 * n5 + v6 * n6 + v7 * n7;
  }
  for (; i + 4 <= end; i += 4) {
    int s0 = csr[i], s1 = csr[i + 1], s2 = csr[i + 2], s3 = csr[i + 3];
    float n0 = dis[s0], n1 = dis[s1], n2 = dis[s2], n3 = dis[s3];
    float v0 = y[(size_t)s0 * 64 + lane];
    float v1 = y[(size_t)s1 * 64 + lane];
    float v2 = y[(size_t)s2 * 64 + lane];
    float v3 = y[(size_t)s3 * 64 + lane];
    acc += v0 * n0 + v1 * n1 + v2 * n2 + v3 * n3;
  }
  for (; i < end; ++i) {
    int s = csr[i];
    acc += y[(size_t)s * 64 + lane] * dis[s];
  }
  acc = acc * dis[w] + bias[lane];
  if (dorelu) acc = fmaxf(acc, 0.f);
  out[(size_t)w * 64 + lane] = acc;
}

extern "C" void kernel_launch(void* const* d_in, const int* in_sizes, int n_in,
                              void* d_out, int out_size, void* d_ws, size_t ws_size,
                              hipStream_t stream) {
  const float* inp  = (const float*)d_in[0];
  const float* hid  = (const float*)d_in[1];
  const int*   eidx = (const int*)d_in[2];
  const float* encw = (const float*)d_in[3];
  const float* encb = (const float*)d_in[4];
  const float* wih  = (const float*)d_in[5];
  const float* whh  = (const float*)d_in[6];
  const float* bih  = (const float*)d_in[7];
  const float* bhh  = (const float*)d_in[8];
  const float* g1w  = (const float*)d_in[9];
  const float* g1b  = (const float*)d_in[10];
  const float* g2w  = (const float*)d_in[11];
  const float* g2b  = (const float*)d_in[12];
  const float* qw   = (const float*)d_in[13];
  const float* qb   = (const float*)d_in[14];

  int n = in_sizes[1] / H;   // 200000
  int e = in_sizes[2] / 2;   // 3200000
  const int* esrc = eidx;
  const int* edst = eidx + e;

  float* qout = (float*)d_out;
  float* h2o  = (float*)d_out + (size_t)n * AHEAD;

  // workspace carve
  char* w = (char*)d_ws;
  unsigned short* p_enc = (unsigned short*)w; w += 9 * 4 * 2048;   // 73728
  unsigned short* p_wih = (unsigned short*)w; w += 2 * 12 * 2048;  // 49152
  unsigned short* p_whh = (unsigned short*)w; w += 2 * 12 * 2048;
  unsigned short* p_g1  = (unsigned short*)w; w += 2 * 4 * 2048;   // 16384
  unsigned short* p_g2  = (unsigned short*)w; w += 2 * 4 * 2048;
  unsigned short* p_q   = (unsigned short*)w; w += 2 * 1 * 2048;   // 4096
  int* deg       = (int*)w;   w += (size_t)n * 4;
  int* part      = (int*)w;   w += (size_t)n * 4;
  int* bsums     = (int*)w;   w += 4096;
  int* row_start = (int*)w;   w += ((size_t)n + 1) * 4;
  int* cursor    = (int*)w;   w += (size_t)n * 4;
  float* dis     = (float*)w; w += (size_t)n * 4;
  int* csr       = (int*)w;   w += (size_t)(e + n) * 4;
  w = (char*)(((uintptr_t)w + 15) & ~(uintptr_t)15);
  float* h1buf   = (float*)w; w += (size_t)n * H * 4;
  float* ybuf    = (float*)w; w += (size_t)n * H * 4;
  float* xbuf    = (float*)w; w += (size_t)n * H * 4;

  int nb = (n + 255) / 256;
  int total = e + n;

  // weight packs (tiny grids)
  hipLaunchKernelGGL(k_packw, dim3(9), dim3(256), 0, stream, encw, 64, DIN, 9, 4, p_enc);
  hipLaunchKernelGGL(k_packw, dim3(6), dim3(256), 0, stream, wih, 192, 64, 2, 12, p_wih);
  hipLaunchKernelGGL(k_packw, dim3(6), dim3(256), 0, stream, whh, 192, 64, 2, 12, p_whh);
  hipLaunchKernelGGL(k_packw, dim3(2), dim3(256), 0, stream, g1w, 64, 64, 2, 4, p_g1);
  hipLaunchKernelGGL(k_packw, dim3(2), dim3(256), 0, stream, g2w, 64, 64, 2, 4, p_g2);
  hipLaunchKernelGGL(k_packw, dim3(1), dim3(256), 0, stream, qw, AHEAD, 64, 2, 1, p_q);

  // graph prep
  hipLaunchKernelGGL(k_init_deg, dim3(nb), dim3(256), 0, stream, deg, n);
  hipLaunchKernelGGL(k_deg, dim3((e + 255) / 256), dim3(256), 0, stream, edst, deg, e);
  hipLaunchKernelGGL(k_scan1, dim3(nb), dim3(256), 0, stream, deg, part, bsums, n);
  hipLaunchKernelGGL(k_scan2, dim3(1), dim3(1024), 0, stream, bsums, nb);
  hipLaunchKernelGGL(k_scanfin, dim3((n + 1 + 255) / 256), dim3(256), 0, stream,
                     part, bsums, deg, row_start, cursor, dis, n, total);
  hipLaunchKernelGGL(k_fill, dim3((total + 255) / 256), dim3(256), 0, stream,
                     esrc, edst, cursor, csr, e, n);

  // dense pipeline (MFMA)
  hipLaunchKernelGGL(k_enc_mfma, dim3((n + 31) / 32), dim3(128), 0, stream,
                     inp, p_enc, encb, h1buf, n);
  hipLaunchKernelGGL(k_gru_mfma, dim3((n + 63) / 64), dim3(256), 0, stream,
                     h1buf, hid, p_wih, p_whh, bih, bhh, h2o, n);

  int aggblocks = (int)(((size_t)n * 64 + 255) / 256);
  hipLaunchKernelGGL(k_lin_mfma, dim3((n + 63) / 64), dim3(256), 0, stream, h2o, p_g1, ybuf, n);
  hipLaunchKernelGGL(k_agg, dim3(aggblocks), dim3(256), 0, stream,
                     ybuf, row_start, csr, dis, g1b, xbuf, n, 1);
  hipLaunchKernelGGL(k_lin_mfma, dim3((n + 63) / 64), dim3(256), 0, stream, xbuf, p_g2, ybuf, n);
  hipLaunchKernelGGL(k_agg, dim3(aggblocks), dim3(256), 0, stream,
                     ybuf, row_start, csr, dis, g2b, xbuf, n, 0);
  hipLaunchKernelGGL(k_q_mfma, dim3((n + 63) / 64), dim3(256), 0, stream, xbuf, p_q, qb, qout, n);
}

// Round 5
// 1201.709 us; speedup vs baseline: 2.5753x; 1.1501x over previous
//
#include <hip/hip_runtime.h>
#include <stdint.h>

#define H 64
#define DIN 275
#define AHEAD 14
#define EPB 8192  // edges per scatter block

typedef __attribute__((ext_vector_type(8))) short s16x8;   // 8 bf16 = 4 VGPR
typedef __attribute__((ext_vector_type(4))) float f32x4;

#define MFMA16(a, b, c) __builtin_amdgcn_mfma_f32_16x16x32_bf16((a), (b), (c), 0, 0, 0)

__device__ __forceinline__ unsigned short bf16_rn(float x) {
  unsigned u = __float_as_uint(x);
  return (unsigned short)((u + 0x7FFFu + ((u >> 16) & 1u)) >> 16);
}
__device__ __forceinline__ float bf16f(unsigned short h) {
  return __uint_as_float(((unsigned)h) << 16);
}
// split 8 fp32 -> bf16 hi + bf16 lo fragments (error ~2^-17 rel)
__device__ __forceinline__ void cvt8(const float (&v)[8], s16x8& hi, s16x8& lo) {
#pragma unroll
  for (int j = 0; j < 8; ++j) {
    unsigned short h = bf16_rn(v[j]);
    hi[j] = (short)h;
    lo[j] = (short)bf16_rn(v[j] - bf16f(h));
  }
}

// ---------- weight pre-pack into B-fragment layout (proven) ----------
__global__ void k_packw(const float* __restrict__ W, int F_real, int K_real,
                        int KT, int FT, unsigned short* __restrict__ pack) {
  int idx = blockIdx.x * 256 + threadIdx.x;
  int total = KT * FT * 64;
  if (idx >= total) return;
  int lane = idx & 63;
  int t = idx >> 6;
  int ft = t % FT, kt = t / FT;
  int f = ft * 16 + (lane & 15);
  int kb = kt * 32 + (lane >> 4) * 8;
  unsigned short* base = pack + (size_t)(kt * FT + ft) * 2 * 512;
#pragma unroll
  for (int j = 0; j < 8; ++j) {
    int k = kb + j;
    float v = (f < F_real && k < K_real) ? W[(size_t)f * K_real + k] : 0.f;
    unsigned short h = bf16_rn(v);
    base[lane * 8 + j] = h;
    base[512 + lane * 8 + j] = bf16_rn(v - bf16f(h));
  }
}

// ---------- graph path: bucket semisort (bucket = dst >> 8) ----------
__global__ void k_zero(int* __restrict__ p) {
  int i = blockIdx.x * 256 + threadIdx.x;
  if (i < 1024) p[i] = 0;
}

__global__ void k_hist(const int* __restrict__ dst, int* __restrict__ bcnt, int e) {
  __shared__ int h[1024];
  for (int i = threadIdx.x; i < 1024; i += 256) h[i] = 0;
  __syncthreads();
  int stride = gridDim.x * 256;
  for (int i = blockIdx.x * 256 + threadIdx.x; i < e; i += stride)
    atomicAdd(&h[dst[i] >> 8], 1);
  __syncthreads();
  for (int i = threadIdx.x; i < 1024; i += 256)
    if (h[i]) atomicAdd(&bcnt[i], h[i]);
}

// exclusive scan over bucket counts (same pattern as proven k_scan2)
__global__ void k_bscan(const int* __restrict__ cnt, int* __restrict__ base,
                        int* __restrict__ cursor, int nb) {
  int tid = threadIdx.x;  // 1024 threads, nb <= 1024
  int v = (tid < nb) ? cnt[tid] : 0;
  int lane = tid & 63, wv = tid >> 6;
  int x = v;
#pragma unroll
  for (int d = 1; d < 64; d <<= 1) {
    int y = __shfl_up(x, d, 64);
    if (lane >= d) x += y;
  }
  __shared__ int ws_[16];
  if (lane == 63) ws_[wv] = x;
  __syncthreads();
  int off = 0;
  for (int i = 0; i < wv; ++i) off += ws_[i];
  int excl = x + off - v;
  if (tid < nb) { base[tid] = excl; cursor[tid] = excl; }
}

// block-exclusive chunk claims -> pairs runs are bucket-grouped (L2 write-merge)
__global__ __launch_bounds__(256) void k_scatter(
    const int* __restrict__ src, const int* __restrict__ dst,
    int* __restrict__ cursor, int2* __restrict__ pairs, int e) {
  __shared__ int hist[1024];
  __shared__ int gbase[1024];
  int tid = threadIdx.x;
  int e0 = blockIdx.x * EPB;
#pragma unroll
  for (int q = 0; q < 4; ++q) hist[tid * 4 + q] = 0;
  __syncthreads();
  // phase A: local count
  for (int k = 0; k < EPB / 256; ++k) {
    int i = e0 + k * 256 + tid;
    if (i < e) atomicAdd(&hist[dst[i] >> 8], 1);
  }
  __syncthreads();
  // phase B: claim global chunks, reset local cursors
#pragma unroll
  for (int q = 0; q < 4; ++q) {
    int b = tid * 4 + q;
    int c = hist[b];
    if (c > 0) {
      gbase[b] = atomicAdd(&cursor[b], c);
      hist[b] = 0;
    }
  }
  __syncthreads();
  // phase C: write pairs into owned runs
  for (int k = 0; k < EPB / 256; ++k) {
    int i = e0 + k * 256 + tid;
    if (i < e) {
      int s = src[i], d = dst[i];
      int b = d >> 8;
      int lr = atomicAdd(&hist[b], 1);
      pairs[(size_t)gbase[b] + lr] = make_int2(s, d);
    }
  }
}

// per-bucket node in-degree from pairs -> deg[] (+1 self-loop)
__global__ void k_degb(const int2* __restrict__ pairs, const int* __restrict__ bbase,
                       const int* __restrict__ bcnt, int* __restrict__ deg, int n) {
  __shared__ int c[256];
  int b = blockIdx.x, tid = threadIdx.x;
  c[tid] = 0;
  __syncthreads();
  int base = bbase[b], cnt = bcnt[b];
  for (int i = tid; i < cnt; i += 256)
    atomicAdd(&c[pairs[base + i].y & 255], 1);
  __syncthreads();
  int node = b * 256 + tid;
  if (node < n) deg[node] = c[tid] + 1;
}

// ---------- 2-level exclusive scan over deg -> row_start (proven) ----------
__global__ void k_scan1(const int* __restrict__ in, int* __restrict__ part,
                        int* __restrict__ bsums, int n) {
  int tid = threadIdx.x;
  int gid = blockIdx.x * 256 + tid;
  int v = (gid < n) ? in[gid] : 0;
  int lane = tid & 63, wv = tid >> 6;
  int x = v;
#pragma unroll
  for (int d = 1; d < 64; d <<= 1) {
    int y = __shfl_up(x, d, 64);
    if (lane >= d) x += y;
  }
  __shared__ int ws_[4];
  if (lane == 63) ws_[wv] = x;
  __syncthreads();
  int off = 0;
  for (int i = 0; i < wv; ++i) off += ws_[i];
  int incl = x + off;
  if (gid < n) part[gid] = incl - v;
  if (tid == 255) bsums[blockIdx.x] = incl;
}

__global__ void k_scan2(int* __restrict__ bsums, int nb) {
  int tid = threadIdx.x;  // block of 1024, nb <= 1024
  int v = (tid < nb) ? bsums[tid] : 0;
  int lane = tid & 63, wv = tid >> 6;
  int x = v;
#pragma unroll
  for (int d = 1; d < 64; d <<= 1) {
    int y = __shfl_up(x, d, 64);
    if (lane >= d) x += y;
  }
  __shared__ int ws_[16];
  if (lane == 63) ws_[wv] = x;
  __syncthreads();
  int off = 0;
  for (int i = 0; i < wv; ++i) off += ws_[i];
  int incl = x + off;
  if (tid < nb) bsums[tid] = incl - v;
}

__global__ void k_scanfin(const int* __restrict__ part, const int* __restrict__ bsums,
                          const int* __restrict__ deg, int* __restrict__ row_start,
                          int* __restrict__ cursor, float* __restrict__ dis,
                          int n, int total) {
  int gid = blockIdx.x * 256 + threadIdx.x;
  if (gid < n) {
    int rs = part[gid] + bsums[gid >> 8];
    row_start[gid] = rs;
    cursor[gid] = rs;
    dis[gid] = rsqrtf((float)deg[gid]);
  } else if (gid == n) {
    row_start[n] = total;
  }
}

// csr fill from bucket-grouped pairs: a block's writes land in ~17KB window
__global__ void k_fill2(const int2* __restrict__ pairs, int* __restrict__ cursor,
                        int* __restrict__ csr, int e, int n) {
  int i = blockIdx.x * 256 + threadIdx.x;
  if (i >= e + n) return;
  int s, d;
  if (i < e) { int2 p = pairs[i]; s = p.x; d = p.y; }
  else       { s = i - e; d = s; }      // self loops
  int pos = atomicAdd(&cursor[d], 1);
  csr[pos] = s;
}

// ---------- encoder via MFMA (proven) ----------
__global__ __launch_bounds__(128, 2) void k_enc_mfma(
    const float* __restrict__ inp, const unsigned short* __restrict__ wp,
    const float* __restrict__ benc, float* __restrict__ h1o, int n) {
  __shared__ float lds[2][16 * DIN];
  int tid = threadIdx.x;
  int wv = tid >> 6, lane = tid & 63;
  long long node0 = ((long long)blockIdx.x * 2 + wv) * 16;
  if (node0 >= n) return;
  float* L = lds[wv];

  const float4* src = (const float4*)(inp + (size_t)node0 * DIN);
#pragma unroll
  for (int i = 0; i < 17; ++i) {
    float4 t = src[i * 64 + lane];
    *(float4*)(L + (i * 64 + lane) * 4) = t;
  }
  if (lane < 48) L[4352 + lane] = inp[(size_t)node0 * DIN + 4352 + lane];

  int r = lane & 15, kq = lane >> 4;
  f32x4 acc[4];
#pragma unroll
  for (int i = 0; i < 4; ++i) acc[i] = (f32x4){0.f, 0.f, 0.f, 0.f};

  const s16x8* bp = (const s16x8*)wp;
#pragma unroll
  for (int kc = 0; kc < 9; ++kc) {
    int kb = kc * 32 + kq * 8;
    float vv[8];
#pragma unroll
    for (int j = 0; j < 8; ++j) {
      int k = kb + j;
      float t = 0.f;
      if (kc < 8 || k < DIN) t = L[r * DIN + k];
      vv[j] = t;
    }
    s16x8 ah, al;
    cvt8(vv, ah, al);
#pragma unroll
    for (int ft = 0; ft < 4; ++ft) {
      s16x8 bh = bp[((kc * 4 + ft) * 2 + 0) * 64 + lane];
      s16x8 bl = bp[((kc * 4 + ft) * 2 + 1) * 64 + lane];
      acc[ft] = MFMA16(ah, bh, acc[ft]);
      acc[ft] = MFMA16(al, bh, acc[ft]);
      acc[ft] = MFMA16(ah, bl, acc[ft]);
    }
  }

  int fc = lane & 15, rq = lane >> 4;
#pragma unroll
  for (int ft = 0; ft < 4; ++ft) {
    float b = benc[ft * 16 + fc];
#pragma unroll
    for (int rg = 0; rg < 4; ++rg) {
      long long node = node0 + rq * 4 + rg;
      if (node < n)
        h1o[(size_t)node * 64 + ft * 16 + fc] = fmaxf(acc[ft][rg] + b, 0.f);
    }
  }
}

// ---------- GRU via MFMA (proven) ----------
__global__ __launch_bounds__(256, 2) void k_gru_mfma(
    const float* __restrict__ h1g, const float* __restrict__ hid,
    const unsigned short* __restrict__ wpih, const unsigned short* __restrict__ wphh,
    const float* __restrict__ bih, const float* __restrict__ bhh,
    float* __restrict__ h2o, int n) {
  int tid = threadIdx.x;
  int wv = tid >> 6, lane = tid & 63;
  long long node0 = ((long long)blockIdx.x * 4 + wv) * 16;
  if (node0 >= n) return;
  int r = lane & 15, kq = lane >> 4;

  s16x8 xh[2], xl[2], hh[2], hl[2];
#pragma unroll
  for (int kc = 0; kc < 2; ++kc) {
    float vv[8];
    const float4* p = (const float4*)(h1g + (size_t)(node0 + r) * 64 + kc * 32 + kq * 8);
    float4 a = p[0], b = p[1];
    vv[0] = a.x; vv[1] = a.y; vv[2] = a.z; vv[3] = a.w;
    vv[4] = b.x; vv[5] = b.y; vv[6] = b.z; vv[7] = b.w;
    cvt8(vv, xh[kc], xl[kc]);
    const float4* q = (const float4*)(hid + (size_t)(node0 + r) * 64 + kc * 32 + kq * 8);
    float4 c = q[0], d = q[1];
    vv[0] = c.x; vv[1] = c.y; vv[2] = c.z; vv[3] = c.w;
    vv[4] = d.x; vv[5] = d.y; vv[6] = d.z; vv[7] = d.w;
    cvt8(vv, hh[kc], hl[kc]);
  }

  f32x4 ai[12], ag[12];
#pragma unroll
  for (int i = 0; i < 12; ++i) {
    ai[i] = (f32x4){0.f, 0.f, 0.f, 0.f};
    ag[i] = (f32x4){0.f, 0.f, 0.f, 0.f};
  }

  const s16x8* bpI = (const s16x8*)wpih;
  const s16x8* bpH = (const s16x8*)wphh;
#pragma unroll
  for (int kc = 0; kc < 2; ++kc) {
#pragma unroll
    for (int ft = 0; ft < 12; ++ft) {
      int t = (kc * 12 + ft) * 2;
      s16x8 bh = bpI[(t + 0) * 64 + lane];
      s16x8 bl = bpI[(t + 1) * 64 + lane];
      ai[ft] = MFMA16(xh[kc], bh, ai[ft]);
      ai[ft] = MFMA16(xl[kc], bh, ai[ft]);
      ai[ft] = MFMA16(xh[kc], bl, ai[ft]);
      s16x8 ch = bpH[(t + 0) * 64 + lane];
      s16x8 cl = bpH[(t + 1) * 64 + lane];
      ag[ft] = MFMA16(hh[kc], ch, ag[ft]);
      ag[ft] = MFMA16(hl[kc], ch, ag[ft]);
      ag[ft] = MFMA16(hh[kc], cl, ag[ft]);
    }
  }

  int fc = lane & 15, rq = lane >> 4;
#pragma unroll
  for (int ft = 0; ft < 4; ++ft) {
    int f = ft * 16 + fc;
    float bir = bih[f], biz = bih[64 + f], bin = bih[128 + f];
    float bhr = bhh[f], bhz = bhh[64 + f], bhn = bhh[128 + f];
#pragma unroll
    for (int rg = 0; rg < 4; ++rg) {
      long long node = node0 + rq * 4 + rg;
      float ir = ai[ft][rg] + bir, hr2 = ag[ft][rg] + bhr;
      float iz = ai[ft + 4][rg] + biz, hz = ag[ft + 4][rg] + bhz;
      float in2 = ai[ft + 8][rg] + bin, hn = ag[ft + 8][rg] + bhn;
      float rr = 1.f / (1.f + __expf(-(ir + hr2)));
      float zz = 1.f / (1.f + __expf(-(iz + hz)));
      float nn = tanhf(in2 + rr * hn);
      float hprev = hid[(size_t)node * 64 + f];
      if (node < n)
        h2o[(size_t)node * 64 + f] = (1.f - zz) * nn + zz * hprev;
    }
  }
}

// ---------- GCN linear via MFMA (proven) ----------
__global__ __launch_bounds__(256, 4) void k_lin_mfma(
    const float* __restrict__ x, const unsigned short* __restrict__ wp,
    float* __restrict__ y, int n) {
  int tid = threadIdx.x;
  int wv = tid >> 6, lane = tid & 63;
  long long node0 = ((long long)blockIdx.x * 4 + wv) * 16;
  if (node0 >= n) return;
  int r = lane & 15, kq = lane >> 4;

  s16x8 ah[2], al[2];
#pragma unroll
  for (int kc = 0; kc < 2; ++kc) {
    float vv[8];
    const float4* p = (const float4*)(x + (size_t)(node0 + r) * 64 + kc * 32 + kq * 8);
    float4 a = p[0], b = p[1];
    vv[0] = a.x; vv[1] = a.y; vv[2] = a.z; vv[3] = a.w;
    vv[4] = b.x; vv[5] = b.y; vv[6] = b.z; vv[7] = b.w;
    cvt8(vv, ah[kc], al[kc]);
  }

  f32x4 acc[4];
#pragma unroll
  for (int i = 0; i < 4; ++i) acc[i] = (f32x4){0.f, 0.f, 0.f, 0.f};
  const s16x8* bp = (const s16x8*)wp;
#pragma unroll
  for (int kc = 0; kc < 2; ++kc) {
#pragma unroll
    for (int ft = 0; ft < 4; ++ft) {
      int t = (kc * 4 + ft) * 2;
      s16x8 bh = bp[(t + 0) * 64 + lane];
      s16x8 bl = bp[(t + 1) * 64 + lane];
      acc[ft] = MFMA16(ah[kc], bh, acc[ft]);
      acc[ft] = MFMA16(al[kc], bh, acc[ft]);
      acc[ft] = MFMA16(ah[kc], bl, acc[ft]);
    }
  }

  int fc = lane & 15, rq = lane >> 4;
#pragma unroll
  for (int ft = 0; ft < 4; ++ft)
#pragma unroll
    for (int rg = 0; rg < 4; ++rg) {
      long long node = node0 + rq * 4 + rg;
      if (node < n) y[(size_t)node * 64 + ft * 16 + fc] = acc[ft][rg];
    }
}

// ---------- Q head via MFMA (proven) ----------
__global__ __launch_bounds__(256, 4) void k_q_mfma(
    const float* __restrict__ x, const unsigned short* __restrict__ wp,
    const float* __restrict__ qb, float* __restrict__ qout, int n) {
  int tid = threadIdx.x;
  int wv = tid >> 6, lane = tid & 63;
  long long node0 = ((long long)blockIdx.x * 4 + wv) * 16;
  if (node0 >= n) return;
  int r = lane & 15, kq = lane >> 4;

  s16x8 ah[2], al[2];
#pragma unroll
  for (int kc = 0; kc < 2; ++kc) {
    float vv[8];
    const float4* p = (const float4*)(x + (size_t)(node0 + r) * 64 + kc * 32 + kq * 8);
    float4 a = p[0], b = p[1];
    vv[0] = a.x; vv[1] = a.y; vv[2] = a.z; vv[3] = a.w;
    vv[4] = b.x; vv[5] = b.y; vv[6] = b.z; vv[7] = b.w;
    cvt8(vv, ah[kc], al[kc]);
  }

  f32x4 acc = (f32x4){0.f, 0.f, 0.f, 0.f};
  const s16x8* bp = (const s16x8*)wp;
#pragma unroll
  for (int kc = 0; kc < 2; ++kc) {
    s16x8 bh = bp[(kc * 2 + 0) * 64 + lane];
    s16x8 bl = bp[(kc * 2 + 1) * 64 + lane];
    acc = MFMA16(ah[kc], bh, acc);
    acc = MFMA16(al[kc], bh, acc);
    acc = MFMA16(ah[kc], bl, acc);
  }

  int fc = lane & 15, rq = lane >> 4;
  float b = (fc < AHEAD) ? qb[fc] : 0.f;
#pragma unroll
  for (int rg = 0; rg < 4; ++rg) {
    long long node = node0 + rq * 4 + rg;
    if (fc < AHEAD && node < n) qout[(size_t)node * AHEAD + fc] = acc[rg] + b;
  }
}

// ---------- gather aggregation (proven): wave = dst node, lane = feature ----------
__global__ __launch_bounds__(256, 8) void k_agg(
    const float* __restrict__ y, const int* __restrict__ row_start,
    const int* __restrict__ csr, const float* __restrict__ dis,
    const float* __restrict__ bias, float* __restrict__ out,
    int n, int dorelu) {
  int t = blockIdx.x * 256 + threadIdx.x;
  int w = t >> 6;
  int lane = t & 63;
  if (w >= n) return;
  w = __builtin_amdgcn_readfirstlane(w);
  int beg = row_start[w], end = row_start[w + 1];
  float acc = 0.f;
  int i = beg;
  for (; i + 8 <= end; i += 8) {
    int s0 = csr[i + 0], s1 = csr[i + 1], s2 = csr[i + 2], s3 = csr[i + 3];
    int s4 = csr[i + 4], s5 = csr[i + 5], s6 = csr[i + 6], s7 = csr[i + 7];
    float n0 = dis[s0], n1 = dis[s1], n2 = dis[s2], n3 = dis[s3];
    float n4 = dis[s4], n5 = dis[s5], n6 = dis[s6], n7 = dis[s7];
    float v0 = y[(size_t)s0 * 64 + lane];
    float v1 = y[(size_t)s1 * 64 + lane];
    float v2 = y[(size_t)s2 * 64 + lane];
    float v3 = y[(size_t)s3 * 64 + lane];
    float v4 = y[(size_t)s4 * 64 + lane];
    float v5 = y[(size_t)s5 * 64 + lane];
    float v6 = y[(size_t)s6 * 64 + lane];
    float v7 = y[(size_t)s7 * 64 + lane];
    acc += v0 * n0 + v1 * n1 + v2 * n2 + v3 * n3;
    acc += v4 * n4 + v5 * n5 + v6 * n6 + v7 * n7;
  }
  for (; i + 4 <= end; i += 4) {
    int s0 = csr[i], s1 = csr[i + 1], s2 = csr[i + 2], s3 = csr[i + 3];
    float n0 = dis[s0], n1 = dis[s1], n2 = dis[s2], n3 = dis[s3];
    float v0 = y[(size_t)s0 * 64 + lane];
    float v1 = y[(size_t)s1 * 64 + lane];
    float v2 = y[(size_t)s2 * 64 + lane];
    float v3 = y[(size_t)s3 * 64 + lane];
    acc += v0 * n0 + v1 * n1 + v2 * n2 + v3 * n3;
  }
  for (; i < end; ++i) {
    int s = csr[i];
    acc += y[(size_t)s * 64 + lane] * dis[s];
  }
  acc = acc * dis[w] + bias[lane];
  if (dorelu) acc = fmaxf(acc, 0.f);
  out[(size_t)w * 64 + lane] = acc;
}

extern "C" void kernel_launch(void* const* d_in, const int* in_sizes, int n_in,
                              void* d_out, int out_size, void* d_ws, size_t ws_size,
                              hipStream_t stream) {
  const float* inp  = (const float*)d_in[0];
  const float* hid  = (const float*)d_in[1];
  const int*   eidx = (const int*)d_in[2];
  const float* encw = (const float*)d_in[3];
  const float* encb = (const float*)d_in[4];
  const float* wih  = (const float*)d_in[5];
  const float* whh  = (const float*)d_in[6];
  const float* bih  = (const float*)d_in[7];
  const float* bhh  = (const float*)d_in[8];
  const float* g1w  = (const float*)d_in[9];
  const float* g1b  = (const float*)d_in[10];
  const float* g2w  = (const float*)d_in[11];
  const float* g2b  = (const float*)d_in[12];
  const float* qw   = (const float*)d_in[13];
  const float* qb   = (const float*)d_in[14];

  int n = in_sizes[1] / H;   // 200000
  int e = in_sizes[2] / 2;   // 3200000
  const int* esrc = eidx;
  const int* edst = eidx + e;

  float* qout = (float*)d_out;
  float* h2o  = (float*)d_out + (size_t)n * AHEAD;

  int nbuck = (n + 255) >> 8;   // 782 <= 1024
  int nb = (n + 255) / 256;
  int total = e + n;

  // workspace carve (~146 MB, below proven 173 MB)
  char* w = (char*)d_ws;
  unsigned short* p_enc = (unsigned short*)w; w += 9 * 4 * 2048;
  unsigned short* p_wih = (unsigned short*)w; w += 2 * 12 * 2048;
  unsigned short* p_whh = (unsigned short*)w; w += 2 * 12 * 2048;
  unsigned short* p_g1  = (unsigned short*)w; w += 2 * 4 * 2048;
  unsigned short* p_g2  = (unsigned short*)w; w += 2 * 4 * 2048;
  unsigned short* p_q   = (unsigned short*)w; w += 2 * 1 * 2048;
  int* bcnt      = (int*)w;   w += 4096 * 4;
  int* bbase     = (int*)w;   w += 4096 * 4;
  int* bcur      = (int*)w;   w += 4096 * 4;
  int* deg       = (int*)w;   w += (size_t)n * 4;
  int* part      = (int*)w;   w += (size_t)n * 4;
  int* bsums     = (int*)w;   w += 4096;
  int* row_start = (int*)w;   w += ((size_t)n + 1) * 4;
  int* cursor    = (int*)w;   w += (size_t)n * 4;
  float* dis     = (float*)w; w += (size_t)n * 4;
  int* csr       = (int*)w;   w += (size_t)(e + n) * 4;
  w = (char*)(((uintptr_t)w + 15) & ~(uintptr_t)15);
  int2* pairs    = (int2*)w;  w += (size_t)e * 8;
  float* h1buf   = (float*)w; w += (size_t)n * H * 4;
  float* ybuf    = (float*)w; w += (size_t)n * H * 4;
  float* xbuf    = h1buf;     // alias: h1buf free after GRU

  // weight packs (tiny grids)
  hipLaunchKernelGGL(k_packw, dim3(9), dim3(256), 0, stream, encw, 64, DIN, 9, 4, p_enc);
  hipLaunchKernelGGL(k_packw, dim3(6), dim3(256), 0, stream, wih, 192, 64, 2, 12, p_wih);
  hipLaunchKernelGGL(k_packw, dim3(6), dim3(256), 0, stream, whh, 192, 64, 2, 12, p_whh);
  hipLaunchKernelGGL(k_packw, dim3(2), dim3(256), 0, stream, g1w, 64, 64, 2, 4, p_g1);
  hipLaunchKernelGGL(k_packw, dim3(2), dim3(256), 0, stream, g2w, 64, 64, 2, 4, p_g2);
  hipLaunchKernelGGL(k_packw, dim3(1), dim3(256), 0, stream, qw, AHEAD, 64, 2, 1, p_q);

  // graph path: bucket semisort -> exact CSR (proven consumers)
  hipLaunchKernelGGL(k_zero, dim3(4), dim3(256), 0, stream, bcnt);
  hipLaunchKernelGGL(k_hist, dim3(512), dim3(256), 0, stream, edst, bcnt, e);
  hipLaunchKernelGGL(k_bscan, dim3(1), dim3(1024), 0, stream, bcnt, bbase, bcur, nbuck);
  hipLaunchKernelGGL(k_scatter, dim3((e + EPB - 1) / EPB), dim3(256), 0, stream,
                     esrc, edst, bcur, pairs, e);
  hipLaunchKernelGGL(k_degb, dim3(nbuck), dim3(256), 0, stream, pairs, bbase, bcnt, deg, n);
  hipLaunchKernelGGL(k_scan1, dim3(nb), dim3(256), 0, stream, deg, part, bsums, n);
  hipLaunchKernelGGL(k_scan2, dim3(1), dim3(1024), 0, stream, bsums, nb);
  hipLaunchKernelGGL(k_scanfin, dim3((n + 1 + 255) / 256), dim3(256), 0, stream,
                     part, bsums, deg, row_start, cursor, dis, n, total);
  hipLaunchKernelGGL(k_fill2, dim3((total + 255) / 256), dim3(256), 0, stream,
                     pairs, cursor, csr, e, n);

  // dense pipeline (MFMA, all proven)
  hipLaunchKernelGGL(k_enc_mfma, dim3((n + 31) / 32), dim3(128), 0, stream,
                     inp, p_enc, encb, h1buf, n);
  hipLaunchKernelGGL(k_gru_mfma, dim3((n + 63) / 64), dim3(256), 0, stream,
                     h1buf, hid, p_wih, p_whh, bih, bhh, h2o, n);

  int aggblocks = (int)(((size_t)n * 64 + 255) / 256);
  hipLaunchKernelGGL(k_lin_mfma, dim3((n + 63) / 64), dim3(256), 0, stream, h2o, p_g1, ybuf, n);
  hipLaunchKernelGGL(k_agg, dim3(aggblocks), dim3(256), 0, stream,
                     ybuf, row_start, csr, dis, g1b, xbuf, n, 1);
  hipLaunchKernelGGL(k_lin_mfma, dim3((n + 63) / 64), dim3(256), 0, stream, xbuf, p_g2, ybuf, n);
  hipLaunchKernelGGL(k_agg, dim3(aggblocks), dim3(256), 0, stream,
                     ybuf, row_start, csr, dis, g2b, xbuf, n, 0);
  hipLaunchKernelGGL(k_q_mfma, dim3((n + 63) / 64), dim3(256), 0, stream, xbuf, p_q, qb, qout, n);
}